// Round 6
// baseline (1703.172 us; speedup 1.0000x reference)
//
#include <hip/hip_runtime.h>

typedef unsigned short u16;
typedef unsigned int u32;
typedef __bf16 bf16x8 __attribute__((ext_vector_type(8)));
typedef float f32x4 __attribute__((ext_vector_type(4)));

#define NPAPER 100000
#define NAUTH  50000
#define PHALF  50000
#define AHALF  25000
#define KP 40   // LDS row stride (elems): 80B, 16B-aligned rows -> conflict-free b128

struct alignas(16) U4 { u32 a, b, c, d; };
struct alignas(16) F4 { float x, y, z, w; };

__device__ __forceinline__ float bf2f(u16 u) {
    union { u32 i; float f; } v; v.i = ((u32)u) << 16; return v.f;
}
__device__ __forceinline__ u16 f2bf(float f) {
    union { float f; u32 i; } v; v.f = f;
    u32 u = v.i;
    return (u16)((u + 0x7FFFu + ((u >> 16) & 1u)) >> 16);
}

// flags: [0]=idx_is_int64 [1]=x_is_f32 [2]=W_is_f32 [3]=b_is_f32 [4]=0 const (bf16)
__device__ __forceinline__ float ldf(const void* p, size_t i, int f32) {
    return f32 ? ((const float*)p)[i] : bf2f(((const u16*)p)[i]);
}

__global__ void detect_dtypes(const int* __restrict__ e, const u32* __restrict__ x,
                              const u32* __restrict__ w, const u32* __restrict__ bb,
                              int* __restrict__ flags)
{
    int t = threadIdx.x, wave = t >> 6, lane = t & 63;
    if (wave == 0) {
        int v = e[lane];
        unsigned long long m = __ballot((lane & 1) && v == 0);
        if (lane == 0) { flags[0] = (__popcll(m) >= 24) ? 1 : 0; flags[4] = 0; }
    } else {
        const u32* p = (wave == 1) ? x : ((wave == 2) ? w : bb);
        u32 wd = p[lane];
        int ex = (int)((wd >> 7) & 0xFFu);   // exponent of low-half-as-bf16
        unsigned long long m = __ballot(ex >= 105 && ex <= 140);
        if (lane == 0) flags[wave] = (__popcll(m) >= 40) ? 0 : 1;   // 1 = f32
    }
}

// ---- weight prep (one layer): WTpa[n*256+k] = [Wm0 ; Wr0+Wr1](k,n)
//      WTpb[n*128+k] = Wm1(k,n);  WTa[n*256+k] = [Wm2 ; Wr2](k,n)
__global__ __launch_bounds__(256) void prep_weights(
    const void* __restrict__ Wm, const void* __restrict__ b, const void* __restrict__ Wr,
    u16* __restrict__ WTpa, u16* __restrict__ WTpb, u16* __restrict__ WTa,
    float* __restrict__ biasp, float* __restrict__ biasa,
    const int* __restrict__ flags)
{
    int wf = flags[2], bf = flags[3];
    int tid = blockIdx.x * 256 + threadIdx.x;
    if (tid < 32768) {
        int n = tid >> 8, k = tid & 255;
        float v = (k < 128) ? ldf(Wm, k * 128 + n, wf)
                            : ldf(Wr, (k - 128) * 128 + n, wf)
                            + ldf(Wr, 16384 + (k - 128) * 128 + n, wf);
        WTpa[n * 256 + k] = f2bf(v);
    } else if (tid < 49152) {
        int idx = tid - 32768;
        int n = idx >> 7, k = idx & 127;
        WTpb[n * 128 + k] = f2bf(ldf(Wm, 16384 + k * 128 + n, wf));
    } else if (tid < 81920) {
        int idx = tid - 49152;
        int n = idx >> 8, k = idx & 255;
        float v = (k < 128) ? ldf(Wm, 2 * 16384 + k * 128 + n, wf)
                            : ldf(Wr, 2 * 16384 + (k - 128) * 128 + n, wf);
        WTa[n * 256 + k] = f2bf(v);
    } else if (tid < 82176) {
        int i = tid - 81920;
        if (i < 128) biasp[i] = ldf(b, i, bf) + ldf(b, 128 + i, bf);
        else         biasa[i - 128] = ldf(b, 256 + (i - 128), bf);
    }
}

// ---- aggregation: one wave per edge, dst-range filtered, f32 atomics ----
__global__ __launch_bounds__(256) void agg_kernel(
    const void* __restrict__ x, const int* __restrict__ src,
    const int* __restrict__ dst, int E, int lo, int hi,
    float* __restrict__ S, float* __restrict__ C,
    const int* __restrict__ flags, int xslot)
{
    int wid = (blockIdx.x * 256 + threadIdx.x) >> 6;
    int lane = threadIdx.x & 63;
    if (wid >= E) return;
    int f64 = flags[0], xf32 = flags[xslot];          // wave-uniform
    int ii = f64 ? 2 * wid : wid;
    int d = dst[ii];
    if (d < lo || d >= hi) return;                    // wave-uniform
    int s = src[ii];
    float v0, v1;
    if (xf32) {
        float2 v = ((const float2*)((const float*)x + (size_t)s * 128))[lane];
        v0 = v.x; v1 = v.y;
    } else {
        u32 pk = ((const u32*)((const u16*)x + (size_t)s * 128))[lane];
        v0 = bf2f((u16)(pk & 0xFFFFu));
        v1 = bf2f((u16)(pk >> 16));
    }
    float* bp = S + (size_t)(d - lo) * 128 + lane * 2;
    unsafeAtomicAdd(bp, v0);
    unsafeAtomicAdd(bp + 1, v1);
    if (lane == 0) unsafeAtomicAdd(C + (d - lo), 1.0f);
}

// ---- fused mean/GEMM/bias/accum/relu over rows [rowbase, Mhi) ----
// K=256: [mean | root] @ WT^T ; K=128: [mean] @ WT^T. WT is [128][K] = B^T.
// out_f32: out is float* if 1, bf16(u16)* if 0.
__global__ __launch_bounds__(256) void gemm_kernel(
    const float* __restrict__ S, const float* __restrict__ C,
    int rowbase, int Mhi,
    const void* __restrict__ xroot, const u16* __restrict__ WT,
    const float* __restrict__ bias, void* __restrict__ out, int out_f32,
    int K, int accum, int relu, const int* __restrict__ flags, int rslot)
{
    __shared__ __align__(16) u16 Asm[128 * KP];
    __shared__ __align__(16) u16 Bsm[128 * KP];

    int root_f32 = flags[rslot];

    int t = threadIdx.x;
    int row = t >> 1, kh = t & 1;            // staging: 2 threads/row, 16 elems each
    int grow0 = rowbase + blockIdx.x * 128;
    int grow = grow0 + row;
    int growc = grow < Mhi ? grow : (Mhi - 1);   // clamp loads; stores guarded

    int wave = t >> 6, lane = t & 63;
    int wm = wave >> 1, wn = wave & 1;       // 2x2 wave grid, 64x64 per wave
    int fr = lane & 15, fq = lane >> 4;

    f32x4 acc[4][4] = {};

    int ksteps = K >> 5;
    for (int ks = 0; ks < ksteps; ++ks) {
        int koff = ks * 32 + kh * 16;
        int chunk = koff >> 7;               // 0 = mean, 1 = root (K==256 only)
        int kin = koff & 127;

        alignas(16) u16 av[16];
        alignas(16) u16 bv[16];

        if (chunk == 0) {
            const float* sp = S + (size_t)(growc - rowbase) * 128 + kin;
            float rcp = 1.0f / fmaxf(C[growc - rowbase], 1.0f);
            #pragma unroll
            for (int i = 0; i < 4; ++i) {
                F4 f = ((const F4*)sp)[i];
                av[i * 4 + 0] = f2bf(f.x * rcp);
                av[i * 4 + 1] = f2bf(f.y * rcp);
                av[i * 4 + 2] = f2bf(f.z * rcp);
                av[i * 4 + 3] = f2bf(f.w * rcp);
            }
        } else if (root_f32) {
            const F4* xpq = (const F4*)((const float*)xroot + (size_t)growc * 128 + kin);
            #pragma unroll
            for (int i = 0; i < 4; ++i) {
                F4 f = xpq[i];
                av[i * 4 + 0] = f2bf(f.x);
                av[i * 4 + 1] = f2bf(f.y);
                av[i * 4 + 2] = f2bf(f.z);
                av[i * 4 + 3] = f2bf(f.w);
            }
        } else {
            const U4* xpq = (const U4*)((const u16*)xroot + (size_t)growc * 128 + kin);
            ((U4*)av)[0] = xpq[0];
            ((U4*)av)[1] = xpq[1];
        }
        {
            const U4* wp = (const U4*)(WT + (size_t)row * K + koff);
            ((U4*)bv)[0] = wp[0];
            ((U4*)bv)[1] = wp[1];
        }

        __syncthreads();   // prior iteration's frag reads complete
        {
            u16* ad = Asm + row * KP + kh * 16;
            u16* bd = Bsm + row * KP + kh * 16;
            ((U4*)ad)[0] = ((const U4*)av)[0];
            ((U4*)ad)[1] = ((const U4*)av)[1];
            ((U4*)bd)[0] = ((const U4*)bv)[0];
            ((U4*)bd)[1] = ((const U4*)bv)[1];
        }
        __syncthreads();

        const u16* Ab = Asm + (wm * 64 + fr) * KP + fq * 8;
        const u16* Bb = Bsm + (wn * 64 + fr) * KP + fq * 8;
        bf16x8 af[4], bfv[4];
        #pragma unroll
        for (int r = 0; r < 4; ++r) af[r] = *(const bf16x8*)(Ab + r * 16 * KP);
        #pragma unroll
        for (int c = 0; c < 4; ++c) bfv[c] = *(const bf16x8*)(Bb + c * 16 * KP);
        #pragma unroll
        for (int r = 0; r < 4; ++r)
            #pragma unroll
            for (int c = 0; c < 4; ++c)
                acc[r][c] = __builtin_amdgcn_mfma_f32_16x16x32_bf16(af[r], bfv[c], acc[r][c], 0, 0, 0);
    }

    // epilogue: C/D layout col=lane&15, row=(lane>>4)*4+reg (m89-verified)
    #pragma unroll
    for (int r = 0; r < 4; ++r) {
        int orow0 = grow0 + wm * 64 + r * 16 + fq * 4;
        #pragma unroll
        for (int c = 0; c < 4; ++c) {
            int col = wn * 64 + c * 16 + fr;
            float bvl = bias ? bias[col] : 0.0f;
            #pragma unroll
            for (int g = 0; g < 4; ++g) {
                int orow = orow0 + g;
                if (orow < Mhi) {
                    size_t oi = (size_t)orow * 128 + col;
                    float v = acc[r][c][g] + bvl;
                    if (accum)
                        v += out_f32 ? ((float*)out)[oi] : bf2f(((u16*)out)[oi]);
                    if (relu) v = fmaxf(v, 0.0f);
                    if (out_f32) ((float*)out)[oi] = v;
                    else         ((u16*)out)[oi] = f2bf(v);
                }
            }
        }
    }
}

extern "C" void kernel_launch(void* const* d_in, const int* in_sizes, int n_in,
                              void* d_out, int out_size, void* d_ws, size_t ws_size,
                              hipStream_t stream)
{
    const void* xp  = d_in[0];
    const void* xa  = d_in[1];
    const void* Wm1 = d_in[2];
    const void* b1  = d_in[3];
    const void* Wr1 = d_in[4];
    const void* Wm2 = d_in[5];
    const void* b2  = d_in[6];
    const void* Wr2 = d_in[7];
    const int* e0s = (const int*)d_in[8];
    const int* e0d = (const int*)d_in[9];
    const int* e1s = (const int*)d_in[10];
    const int* e1d = (const int*)d_in[11];
    const int* e2s = (const int*)d_in[12];
    const int* e2d = (const int*)d_in[13];
    int E0 = in_sizes[8], E1 = in_sizes[10], E2 = in_sizes[12];

    // ---- ws layout, ~64.5 MiB total, small/critical data FIRST ----
    char* w = (char*)d_ws;
    int*   flags  = (int*)w;                         // 5 ints
    float* biasp1 = (float*)(w + 256);
    float* biasa1 = biasp1 + 128;
    float* biasp2 = biasa1 + 128;
    float* biasa2 = biasp2 + 128;
    u16*   WTp1a  = (u16*)(w + 2304);                // 128x256
    u16*   WTp1b  = WTp1a + 32768;                   // 128x128
    u16*   WTa1   = WTp1b + 16384;                   // 128x256
    u16*   WTp2a  = WTa1  + 32768;
    u16*   WTp2b  = WTp2a + 32768;
    u16*   WTa2   = WTp2b + 16384;
    u16*   hpw    = WTa2  + 32768;                   // 100000x128 bf16 (layer-1 out)
    u16*   haw    = hpw + (size_t)NPAPER * 128;      // 50000x128 bf16
    float* S      = (float*)(haw + (size_t)NAUTH * 128);  // 50000x128 f32 sums
    float* C      = S + (size_t)PHALF * 128;         // 50000 f32 counts

    float* outp = (float*)d_out;                     // FINAL OUTPUT IS FLOAT32
    float* outa = outp + (size_t)NPAPER * 128;

    detect_dtypes<<<1, 256, 0, stream>>>(e0s, (const u32*)xp, (const u32*)Wm1,
                                         (const u32*)b1, flags);
    prep_weights<<<321, 256, 0, stream>>>(Wm1, b1, Wr1, WTp1a, WTp1b, WTa1,
                                          biasp1, biasa1, flags);
    prep_weights<<<321, 256, 0, stream>>>(Wm2, b2, Wr2, WTp2a, WTp2b, WTa2,
                                          biasp2, biasa2, flags);

    int gE0 = (E0 + 3) / 4, gE1 = (E1 + 3) / 4, gE2 = (E2 + 3) / 4;

    for (int layer = 0; layer < 2; ++layer) {
        const void* fp = layer ? (const void*)hpw : xp;
        const void* fa = layer ? (const void*)haw : xa;
        void* op = layer ? (void*)outp : (void*)hpw;
        void* oa = layer ? (void*)outa : (void*)haw;
        int of32 = layer ? 1 : 0;          // layer 1 -> bf16 ws; layer 2 -> f32 d_out
        u16* WTpa = layer ? WTp2a : WTp1a;
        u16* WTpb = layer ? WTp2b : WTp1b;
        u16* WTau = layer ? WTa2  : WTa1;
        float* bp = layer ? biasp2 : biasp1;
        float* ba = layer ? biasa2 : biasa1;
        int slot = layer ? 4 : 1;          // feature dtype: flags[1] / bf16-const
        int relu = layer ? 0 : 1;

        // papers pass 1: op = mean_cites @ Wm0 + fp @ (Wr0+Wr1) + (b0+b1)
        for (int h = 0; h < 2; ++h) {
            int lo = h * PHALF, hi = lo + PHALF;
            hipMemsetAsync(S, 0, (size_t)PHALF * 128 * 4, stream);
            hipMemsetAsync(C, 0, (size_t)PHALF * 4, stream);
            agg_kernel<<<gE0, 256, 0, stream>>>(fp, e0s, e0d, E0, lo, hi, S, C, flags, slot);
            gemm_kernel<<<(PHALF + 127) / 128, 256, 0, stream>>>(
                S, C, lo, hi, fp, WTpa, bp, op, of32, 256, 0, 0, flags, slot);
        }
        // papers pass 2: op += mean_writes @ Wm1 ; relu (layer 1)
        for (int h = 0; h < 2; ++h) {
            int lo = h * PHALF, hi = lo + PHALF;
            hipMemsetAsync(S, 0, (size_t)PHALF * 128 * 4, stream);
            hipMemsetAsync(C, 0, (size_t)PHALF * 4, stream);
            agg_kernel<<<gE1, 256, 0, stream>>>(fa, e1s, e1d, E1, lo, hi, S, C, flags, slot);
            gemm_kernel<<<(PHALF + 127) / 128, 256, 0, stream>>>(
                S, C, lo, hi, nullptr, WTpb, nullptr, op, of32, 128, 1, relu, flags, slot);
        }
        // authors: oa = mean_wb @ Wm2 + fa @ Wr2 + b2 ; relu (layer 1)
        for (int h = 0; h < 2; ++h) {
            int lo = h * AHALF, hi = lo + AHALF;
            hipMemsetAsync(S, 0, (size_t)AHALF * 128 * 4, stream);
            hipMemsetAsync(C, 0, (size_t)AHALF * 4, stream);
            agg_kernel<<<gE2, 256, 0, stream>>>(fp, e2s, e2d, E2, lo, hi, S, C, flags, slot);
            gemm_kernel<<<(AHALF + 127) / 128, 256, 0, stream>>>(
                S, C, lo, hi, fa, WTau, ba, oa, of32, 256, 0, relu, flags, slot);
        }
    }
}

// Round 7
// 1322.399 us; speedup vs baseline: 1.2879x; 1.2879x over previous
//
#include <hip/hip_runtime.h>

typedef unsigned short u16;
typedef unsigned int u32;
typedef __bf16 bf16x8 __attribute__((ext_vector_type(8)));
typedef float f32x4 __attribute__((ext_vector_type(4)));

#define NPAPER 100000
#define NAUTH  50000
#define PHALF  50000
#define KP 40   // LDS row stride (elems): 80B, 16B-aligned rows -> conflict-free b128

struct alignas(16) U4 { u32 a, b, c, d; };
struct alignas(16) F4 { float x, y, z, w; };

__device__ __forceinline__ float bf2f(u16 u) {
    union { u32 i; float f; } v; v.i = ((u32)u) << 16; return v.f;
}
__device__ __forceinline__ u16 f2bf(float f) {
    union { float f; u32 i; } v; v.f = f;
    u32 u = v.i;
    return (u16)((u + 0x7FFFu + ((u >> 16) & 1u)) >> 16);
}

// flags: [0]=idx_is_int64 [1]=x_is_f32 [2]=W_is_f32 [3]=b_is_f32 [4]=0 const (bf16)
__device__ __forceinline__ float ldf(const void* p, size_t i, int f32) {
    return f32 ? ((const float*)p)[i] : bf2f(((const u16*)p)[i]);
}

__global__ void detect_dtypes(const int* __restrict__ e, const u32* __restrict__ x,
                              const u32* __restrict__ w, const u32* __restrict__ bb,
                              int* __restrict__ flags)
{
    int t = threadIdx.x, wave = t >> 6, lane = t & 63;
    if (wave == 0) {
        int v = e[lane];
        unsigned long long m = __ballot((lane & 1) && v == 0);
        if (lane == 0) { flags[0] = (__popcll(m) >= 24) ? 1 : 0; flags[4] = 0; }
    } else {
        const u32* p = (wave == 1) ? x : ((wave == 2) ? w : bb);
        u32 wd = p[lane];
        int ex = (int)((wd >> 7) & 0xFFu);   // exponent of low-half-as-bf16
        unsigned long long m = __ballot(ex >= 105 && ex <= 140);
        if (lane == 0) flags[wave] = (__popcll(m) >= 40) ? 0 : 1;   // 1 = f32
    }
}

// ---- weight prep (one layer): WTpa[n*256+k] = [Wm0 ; Wr0+Wr1](k,n)
//      WTpb[n*128+k] = Wm1(k,n);  WTa[n*256+k] = [Wm2 ; Wr2](k,n)
__global__ __launch_bounds__(256) void prep_weights(
    const void* __restrict__ Wm, const void* __restrict__ b, const void* __restrict__ Wr,
    u16* __restrict__ WTpa, u16* __restrict__ WTpb, u16* __restrict__ WTa,
    float* __restrict__ biasp, float* __restrict__ biasa,
    const int* __restrict__ flags)
{
    int wf = flags[2], bf = flags[3];
    int tid = blockIdx.x * 256 + threadIdx.x;
    if (tid < 32768) {
        int n = tid >> 8, k = tid & 255;
        float v = (k < 128) ? ldf(Wm, k * 128 + n, wf)
                            : ldf(Wr, (k - 128) * 128 + n, wf)
                            + ldf(Wr, 16384 + (k - 128) * 128 + n, wf);
        WTpa[n * 256 + k] = f2bf(v);
    } else if (tid < 49152) {
        int idx = tid - 32768;
        int n = idx >> 7, k = idx & 127;
        WTpb[n * 128 + k] = f2bf(ldf(Wm, 16384 + k * 128 + n, wf));
    } else if (tid < 81920) {
        int idx = tid - 49152;
        int n = idx >> 8, k = idx & 255;
        float v = (k < 128) ? ldf(Wm, 2 * 16384 + k * 128 + n, wf)
                            : ldf(Wr, 2 * 16384 + (k - 128) * 128 + n, wf);
        WTa[n * 256 + k] = f2bf(v);
    } else if (tid < 82176) {
        int i = tid - 81920;
        if (i < 128) biasp[i] = ldf(b, i, bf) + ldf(b, 128 + i, bf);
        else         biasa[i - 128] = ldf(b, 256 + (i - 128), bf);
    }
}

// ---------------- CSR build ----------------
__global__ __launch_bounds__(256) void hist_kernel(
    const int* __restrict__ dst, int E, int* __restrict__ cnt,
    const int* __restrict__ flags)
{
    int i = blockIdx.x * 256 + threadIdx.x;
    if (i >= E) return;
    int d = dst[flags[0] ? 2 * i : i];
    atomicAdd(&cnt[d], 1);
}

// single-block exclusive scan of cnt[0..N) -> rowptr[0..N], cursor copy
__global__ __launch_bounds__(1024) void scan_kernel(
    const int* __restrict__ cnt, int N,
    int* __restrict__ rowptr, int* __restrict__ cursor)
{
    __shared__ int bs[1024];
    int t = threadIdx.x;
    int chunk = (N + 1023) / 1024;
    int begin = t * chunk; if (begin > N) begin = N;
    int end = begin + chunk; if (end > N) end = N;
    int s = 0;
    for (int i = begin; i < end; ++i) s += cnt[i];
    bs[t] = s;
    __syncthreads();
    for (int off = 1; off < 1024; off <<= 1) {
        int v = (t >= off) ? bs[t - off] : 0;
        __syncthreads();
        bs[t] += v;
        __syncthreads();
    }
    int run = (t == 0) ? 0 : bs[t - 1];
    for (int i = begin; i < end; ++i) {
        rowptr[i] = run; cursor[i] = run;
        run += cnt[i];
    }
    if (end == N) rowptr[N] = run;   // all threads hitting this write same value
}

__global__ __launch_bounds__(256) void scatter_kernel(
    const int* __restrict__ src, const int* __restrict__ dst, int E,
    int* __restrict__ cursor, int* __restrict__ srt,
    const int* __restrict__ flags)
{
    int i = blockIdx.x * 256 + threadIdx.x;
    if (i >= E) return;
    int ii = flags[0] ? 2 * i : i;
    int d = dst[ii];
    int pos = atomicAdd(&cursor[d], 1);
    srt[pos] = src[ii];
}

// ---- CSR gather-mean: one wave per dst row, writes bf16 mean row ----
__global__ __launch_bounds__(256) void agg_csr(
    const void* __restrict__ x, const int* __restrict__ rowptr,
    const int* __restrict__ srt, int lo, int hi,
    u16* __restrict__ M, const int* __restrict__ flags, int xslot)
{
    int r = (blockIdx.x * 256 + threadIdx.x) >> 6;
    int lane = threadIdx.x & 63;
    int d = lo + r;
    if (d >= hi) return;
    int xf32 = flags[xslot];               // wave-uniform
    int e0 = rowptr[d], e1 = rowptr[d + 1];
    float a0 = 0.0f, a1 = 0.0f;
    if (xf32) {
        for (int e = e0; e < e1; ++e) {
            int s = srt[e];
            float2 v = ((const float2*)((const float*)x + (size_t)s * 128))[lane];
            a0 += v.x; a1 += v.y;
        }
    } else {
        for (int e = e0; e < e1; ++e) {
            int s = srt[e];
            u32 pk = ((const u32*)((const u16*)x + (size_t)s * 128))[lane];
            a0 += bf2f((u16)(pk & 0xFFFFu));
            a1 += bf2f((u16)(pk >> 16));
        }
    }
    float rcp = 1.0f / fmaxf((float)(e1 - e0), 1.0f);
    u32 pk = (u32)f2bf(a0 * rcp) | ((u32)f2bf(a1 * rcp) << 16);
    ((u32*)(M + (size_t)r * 128))[lane] = pk;
}

// ---- fused GEMM/bias/accum/relu over rows [rowbase, Mhi) ----
// K=256: [mean | root] @ WT^T ; K=128: [mean] @ WT^T. WT is [128][K] = B^T.
// Mean rows are bf16 in M (row 0 = global row `rowbase`).
__global__ __launch_bounds__(256) void gemm_kernel(
    const u16* __restrict__ M, int rowbase, int Mhi,
    const void* __restrict__ xroot, const u16* __restrict__ WT,
    const float* __restrict__ bias, void* __restrict__ out, int out_f32,
    int K, int accum, int relu, const int* __restrict__ flags, int rslot)
{
    __shared__ __align__(16) u16 Asm[128 * KP];
    __shared__ __align__(16) u16 Bsm[128 * KP];

    int root_f32 = flags[rslot];

    int t = threadIdx.x;
    int row = t >> 1, kh = t & 1;            // staging: 2 threads/row, 16 elems each
    int grow0 = rowbase + blockIdx.x * 128;
    int grow = grow0 + row;
    int growc = grow < Mhi ? grow : (Mhi - 1);   // clamp loads; stores guarded

    int wave = t >> 6, lane = t & 63;
    int wm = wave >> 1, wn = wave & 1;       // 2x2 wave grid, 64x64 per wave
    int fr = lane & 15, fq = lane >> 4;

    f32x4 acc[4][4] = {};

    int ksteps = K >> 5;
    for (int ks = 0; ks < ksteps; ++ks) {
        int koff = ks * 32 + kh * 16;
        int chunk = koff >> 7;               // 0 = mean, 1 = root (K==256 only)
        int kin = koff & 127;

        alignas(16) u16 av[16];
        alignas(16) u16 bv[16];

        if (chunk == 0) {
            const U4* mp = (const U4*)(M + (size_t)(growc - rowbase) * 128 + kin);
            ((U4*)av)[0] = mp[0];
            ((U4*)av)[1] = mp[1];
        } else if (root_f32) {
            const F4* xpq = (const F4*)((const float*)xroot + (size_t)growc * 128 + kin);
            #pragma unroll
            for (int i = 0; i < 4; ++i) {
                F4 f = xpq[i];
                av[i * 4 + 0] = f2bf(f.x);
                av[i * 4 + 1] = f2bf(f.y);
                av[i * 4 + 2] = f2bf(f.z);
                av[i * 4 + 3] = f2bf(f.w);
            }
        } else {
            const U4* xpq = (const U4*)((const u16*)xroot + (size_t)growc * 128 + kin);
            ((U4*)av)[0] = xpq[0];
            ((U4*)av)[1] = xpq[1];
        }
        {
            const U4* wp = (const U4*)(WT + (size_t)row * K + koff);
            ((U4*)bv)[0] = wp[0];
            ((U4*)bv)[1] = wp[1];
        }

        __syncthreads();   // prior iteration's frag reads complete
        {
            u16* ad = Asm + row * KP + kh * 16;
            u16* bd = Bsm + row * KP + kh * 16;
            ((U4*)ad)[0] = ((const U4*)av)[0];
            ((U4*)ad)[1] = ((const U4*)av)[1];
            ((U4*)bd)[0] = ((const U4*)bv)[0];
            ((U4*)bd)[1] = ((const U4*)bv)[1];
        }
        __syncthreads();

        const u16* Ab = Asm + (wm * 64 + fr) * KP + fq * 8;
        const u16* Bb = Bsm + (wn * 64 + fr) * KP + fq * 8;
        bf16x8 af[4], bfv[4];
        #pragma unroll
        for (int r = 0; r < 4; ++r) af[r] = *(const bf16x8*)(Ab + r * 16 * KP);
        #pragma unroll
        for (int c = 0; c < 4; ++c) bfv[c] = *(const bf16x8*)(Bb + c * 16 * KP);
        #pragma unroll
        for (int r = 0; r < 4; ++r)
            #pragma unroll
            for (int c = 0; c < 4; ++c)
                acc[r][c] = __builtin_amdgcn_mfma_f32_16x16x32_bf16(af[r], bfv[c], acc[r][c], 0, 0, 0);
    }

    // epilogue: C/D layout col=lane&15, row=(lane>>4)*4+reg (m89-verified)
    #pragma unroll
    for (int r = 0; r < 4; ++r) {
        int orow0 = grow0 + wm * 64 + r * 16 + fq * 4;
        #pragma unroll
        for (int c = 0; c < 4; ++c) {
            int col = wn * 64 + c * 16 + fr;
            float bvl = bias ? bias[col] : 0.0f;
            #pragma unroll
            for (int g = 0; g < 4; ++g) {
                int orow = orow0 + g;
                if (orow < Mhi) {
                    size_t oi = (size_t)orow * 128 + col;
                    float v = acc[r][c][g] + bvl;
                    if (accum)
                        v += out_f32 ? ((float*)out)[oi] : bf2f(((u16*)out)[oi]);
                    if (relu) v = fmaxf(v, 0.0f);
                    if (out_f32) ((float*)out)[oi] = v;
                    else         ((u16*)out)[oi] = f2bf(v);
                }
            }
        }
    }
}

extern "C" void kernel_launch(void* const* d_in, const int* in_sizes, int n_in,
                              void* d_out, int out_size, void* d_ws, size_t ws_size,
                              hipStream_t stream)
{
    const void* xp  = d_in[0];
    const void* xa  = d_in[1];
    const void* Wm1 = d_in[2];
    const void* b1  = d_in[3];
    const void* Wr1 = d_in[4];
    const void* Wm2 = d_in[5];
    const void* b2  = d_in[6];
    const void* Wr2 = d_in[7];
    const int* e0s = (const int*)d_in[8];
    const int* e0d = (const int*)d_in[9];
    const int* e1s = (const int*)d_in[10];
    const int* e1d = (const int*)d_in[11];
    const int* e2s = (const int*)d_in[12];
    const int* e2d = (const int*)d_in[13];
    int E0 = in_sizes[8], E1 = in_sizes[10], E2 = in_sizes[12];
    if (in_sizes[8] > 300000) { /* int64 detected via flags at runtime anyway */ }

    // ---- ws layout, ~56 MiB total ----
    char* w = (char*)d_ws;
    int*   flags  = (int*)w;                          // 5 ints
    float* biasp1 = (float*)(w + 256);
    float* biasa1 = biasp1 + 128;
    float* biasp2 = biasa1 + 128;
    float* biasa2 = biasp2 + 128;
    u16*   WTp1a  = (u16*)(w + 2304);                 // 128x256
    u16*   WTp1b  = WTp1a + 32768;                    // 128x128
    u16*   WTa1   = WTp1b + 16384;                    // 128x256
    u16*   WTp2a  = WTa1  + 32768;
    u16*   WTp2b  = WTp2a + 32768;
    u16*   WTa2   = WTp2b + 16384;
    int*   rp0    = (int*)(WTa2 + 32768);             // 100001
    int*   rp1    = rp0 + (NPAPER + 1);               // 100001
    int*   rp2    = rp1 + (NPAPER + 1);               // 50001
    int*   cnt    = rp2 + (NAUTH + 1);                // 100000 (shared temp)
    int*   cursor = cnt + NPAPER;                     // 100000 (shared temp)
    int*   srt0   = cursor + NPAPER;                  // 300000
    int*   srt1   = srt0 + 300000;                    // 150000
    int*   srt2   = srt1 + 150000;                    // 150000
    u16*   hpw    = (u16*)(srt2 + 150000);            // 100000x128 bf16
    u16*   haw    = hpw + (size_t)NPAPER * 128;       // 50000x128 bf16
    u16*   Mbuf   = haw + (size_t)NAUTH * 128;        // 50000x128 bf16 mean scratch

    float* outp = (float*)d_out;                      // final output f32
    float* outa = outp + (size_t)NPAPER * 128;

    detect_dtypes<<<1, 256, 0, stream>>>(e0s, (const u32*)xp, (const u32*)Wm1,
                                         (const u32*)b1, flags);
    prep_weights<<<321, 256, 0, stream>>>(Wm1, b1, Wr1, WTp1a, WTp1b, WTa1,
                                          biasp1, biasa1, flags);
    prep_weights<<<321, 256, 0, stream>>>(Wm2, b2, Wr2, WTp2a, WTp2b, WTa2,
                                          biasp2, biasa2, flags);

    // ---- CSR build (3 edge types, sequential reuse of cnt/cursor) ----
    {
        const int* ss[3] = { e0s, e1s, e2s };
        const int* dd[3] = { e0d, e1d, e2d };
        int        EE[3] = { E0, E1, E2 };
        int        NN[3] = { NPAPER, NPAPER, NAUTH };
        int*       rp[3] = { rp0, rp1, rp2 };
        int*       st[3] = { srt0, srt1, srt2 };
        for (int ty = 0; ty < 3; ++ty) {
            hipMemsetAsync(cnt, 0, (size_t)NN[ty] * 4, stream);
            hist_kernel<<<(EE[ty] + 255) / 256, 256, 0, stream>>>(dd[ty], EE[ty], cnt, flags);
            scan_kernel<<<1, 1024, 0, stream>>>(cnt, NN[ty], rp[ty], cursor);
            scatter_kernel<<<(EE[ty] + 255) / 256, 256, 0, stream>>>(
                ss[ty], dd[ty], EE[ty], cursor, st[ty], flags);
        }
    }

    for (int layer = 0; layer < 2; ++layer) {
        const void* fp = layer ? (const void*)hpw : xp;
        const void* fa = layer ? (const void*)haw : xa;
        void* op = layer ? (void*)outp : (void*)hpw;
        void* oa = layer ? (void*)outa : (void*)haw;
        int of32 = layer ? 1 : 0;
        u16* WTpa = layer ? WTp2a : WTp1a;
        u16* WTpb = layer ? WTp2b : WTp1b;
        u16* WTau = layer ? WTa2  : WTa1;
        float* bp = layer ? biasp2 : biasp1;
        float* ba = layer ? biasa2 : biasa1;
        int slot = layer ? 4 : 1;            // feature dtype: flags[1] / bf16-const
        int relu = layer ? 0 : 1;

        // papers pass 1: op = mean_cites @ Wm0 + fp @ (Wr0+Wr1) + (b0+b1)
        for (int h = 0; h < 2; ++h) {
            int lo = h * PHALF, hi = lo + PHALF;
            agg_csr<<<(PHALF + 3) / 4, 256, 0, stream>>>(fp, rp0, srt0, lo, hi, Mbuf, flags, slot);
            gemm_kernel<<<(PHALF + 127) / 128, 256, 0, stream>>>(
                Mbuf, lo, hi, fp, WTpa, bp, op, of32, 256, 0, 0, flags, slot);
        }
        // papers pass 2: op += mean_writes @ Wm1 ; relu (layer 1)
        for (int h = 0; h < 2; ++h) {
            int lo = h * PHALF, hi = lo + PHALF;
            agg_csr<<<(PHALF + 3) / 4, 256, 0, stream>>>(fa, rp1, srt1, lo, hi, Mbuf, flags, slot);
            gemm_kernel<<<(PHALF + 127) / 128, 256, 0, stream>>>(
                Mbuf, lo, hi, nullptr, WTpb, nullptr, op, of32, 128, 1, relu, flags, slot);
        }
        // authors (single pass, 50000 rows): oa = mean_wb @ Wm2 + fa @ Wr2 + b2
        agg_csr<<<(NAUTH + 3) / 4, 256, 0, stream>>>(fp, rp2, srt2, 0, NAUTH, Mbuf, flags, slot);
        gemm_kernel<<<(NAUTH + 127) / 128, 256, 0, stream>>>(
            Mbuf, 0, NAUTH, fa, WTau, ba, oa, of32, 256, 0, relu, flags, slot);
    }
}